// Round 4
// baseline (135.920 us; speedup 1.0000x reference)
//
#include <hip/hip_runtime.h>

// B=8, H=W=128, Cin=128, Cout=256, 3x3 stride2 pad1 -> OH=OW=64.
// Implicit GEMM: M=32768, N=256, K=1152 (9 taps x 128).
// d_out (f32): out_feats[32768*256] | out_coords[32768*3] | alpha[1]
// R11: schedule restructure (T3+T4). 256 blocks x 512 thr, tile 128m x 256n,
//      TRIPLE-buffered LDS (144KB), pipeline depth 2 taps, counted
//      s_waitcnt vmcnt(12/6/0) + raw s_barrier (never drain-to-0 mid-loop).
//      OOB gather lanes -> zero page (exec-uniform VMEM count, required for
//      counted vmcnt). Inner fp8 32x32x16 loop/swizzles/epilogue unchanged.

#define OUT_FEATS_ELEMS (32768 * 256)
#define OUT_COORDS_OFF  OUT_FEATS_ELEMS
#define ALPHA_OFF       (OUT_FEATS_ELEMS + 32768 * 3)

#define F8_BYTES   16777216
#define BW_BYTES   (18 * 16384)
#define ZP_OFF     (F8_BYTES + BW_BYTES)          // 128B zero page after Bw

typedef float v16f __attribute__((ext_vector_type(16)));

__device__ __forceinline__ unsigned pk4fp8(float a, float b, float c, float d) {
    unsigned u = 0;
    u = __builtin_amdgcn_cvt_pk_fp8_f32(a, b, u, false);  // bytes 0,1
    u = __builtin_amdgcn_cvt_pk_fp8_f32(c, d, u, true);   // bytes 2,3
    return u;
}

#define GLOAD_LDS16(SRC, DST)                                                  \
    __builtin_amdgcn_global_load_lds(                                          \
        (const __attribute__((address_space(1))) void*)(SRC),                  \
        (__attribute__((address_space(3))) void*)(DST), 16, 0, 0)

// ---- merged prepass: feats fp32->fp8 (blocks 0..8191) ;
//      weight -> pre-swizzled fp8 images + coords + alpha + zero page ----
// Image[t=nb*9+tap][row 0..127][ch 0..7] (16B chunks):
//   fp8 of w[k = tap*128 + (ch^(row&7))*16 + j][n = nb*128 + row], j=0..15
__global__ void prep_kernel(const float* __restrict__ feats, const float* __restrict__ w,
                            const float* __restrict__ alpha,
                            unsigned char* __restrict__ F8, unsigned char* __restrict__ Bw,
                            float* __restrict__ out) {
    int bid = blockIdx.x;
    if (bid < 8192) {                             // feats: 2097152 threads x 8 elems
        int i = bid * 256 + threadIdx.x;
        const float4* f = (const float4*)feats;
        float4 a = f[2 * i];
        float4 b = f[2 * i + 1];
        uint2 r;
        r.x = pk4fp8(a.x, a.y, a.z, a.w);
        r.y = pk4fp8(b.x, b.y, b.z, b.w);
        ((uint2*)F8)[i] = r;
        return;
    }
    int cid = (bid - 8192) * 256 + threadIdx.x;   // 0..36863
    if (cid < 32768) {                            // coords
        int b = cid >> 12, iy = (cid >> 6) & 63, ix = cid & 63;
        float* c = out + OUT_COORDS_OFF + (size_t)cid * 3;
        c[0] = (float)b; c[1] = (float)iy; c[2] = (float)ix;
        if (cid == 0) out[ALPHA_OFF] = alpha[0];
    }
    if (cid < 8) {                                // 128B zero page (workspace is poisoned)
        uint4 z; z.x = 0u; z.y = 0u; z.z = 0u; z.w = 0u;
        *(uint4*)(Bw + BW_BYTES + cid * 16) = z;
    }
    if (cid < 18432) {                            // 18 images x 128 rows x 8 chunks
        int ch  = cid & 7;
        int row = (cid >> 3) & 127;
        int t   = cid >> 10;                      // 0..17 = nb*9 + tap
        int nb  = (t >= 9) ? 1 : 0;
        int tap = t - 9 * nb;
        int chp = ch ^ (row & 7);
        int n   = (nb << 7) + row;
        int kb  = (tap << 7) + (chp << 4);
        unsigned u[4];
#pragma unroll
        for (int q = 0; q < 4; ++q) {
            float f0 = w[(size_t)(kb + 4 * q + 0) * 256 + n];
            float f1 = w[(size_t)(kb + 4 * q + 1) * 256 + n];
            float f2 = w[(size_t)(kb + 4 * q + 2) * 256 + n];
            float f3 = w[(size_t)(kb + 4 * q + 3) * 256 + n];
            u[q] = pk4fp8(f0, f1, f2, f3);
        }
        uint4 r; r.x = u[0]; r.y = u[1]; r.z = u[2]; r.w = u[3];
        *(uint4*)(Bw + (size_t)cid * 16) = r;
    }
}

// ---- coords for fallback path ----
__global__ void coords_alpha_kernel(float* __restrict__ out, const float* __restrict__ alpha) {
    int i = blockIdx.x * 256 + threadIdx.x;
    int b = i >> 12, iy = (i >> 6) & 63, ix = i & 63;
    float* c = out + OUT_COORDS_OFF + (size_t)i * 3;
    c[0] = (float)b; c[1] = (float)iy; c[2] = (float)ix;
    if (i == 0) out[ALPHA_OFF] = alpha[0];
}

// ---- main implicit GEMM: 128m x 256n tile, BK=128 (one tap/step), fp8 32x32x16 MFMA,
//      3-buffer LDS, depth-2 pipeline with counted vmcnt across raw barriers ----
__global__ __launch_bounds__(512, 2) void gemm_conv_kernel(
    const unsigned char* __restrict__ F8,    // fp8 feats [B*128*128][128]
    const unsigned char* __restrict__ Bw,    // pre-swizzled fp8 B images (18 x 16KB) + 128B zero page
    float* __restrict__ out)                 // [32768][256]
{
    __shared__ unsigned char At[3][128 * 128];   // 16KB each, chunk-swizzled
    __shared__ unsigned char Bs[3][256 * 128];   // 32KB each (full N=256)

    const int tid  = threadIdx.x;
    const int bid  = blockIdx.x;             // 0..255
    // XCD-aware: XCD (bid&7) owns batch bb=(bid&7): per-XCD A set = one 2MB image.
    const int my   = ((bid & 7) << 5) + (bid >> 3);
    const int m0   = my << 7;
    const int bb   = my >> 5;                // == bid & 7
    const int iy0  = (my << 1) & 63;

    const int lane = tid & 63, wave = tid >> 6;  // wave 0..7
    const int wm   = (wave >> 2) << 6;       // 0 / 64
    const int wn   = (wave & 3) << 6;        // 0 / 64 / 128 / 192
    const int l31  = lane & 31;
    const int hh   = lane >> 5;              // k-half select
    const int xorl = l31 & 7;

    // staging: A region = wave*2+it covers 8 rows x 128B; lane -> row=region*8+(lane>>3)
    const int srow = lane >> 3;              // 0..7 sub-row
    const int chp  = (lane & 7) ^ srow;      // swizzled source chunk (row&7 == srow)
    const long rowA0 = (long)bb << 14;
    const unsigned char* zp = Bw + BW_BYTES; // zero page
    // B source: wave w stages Bs rows [w*32, w*32+32) = image (w>>2)*9+tap, rows (w&3)*32..
    const unsigned char* bsrc0 = Bw + ((size_t)((wave >> 2) * 9) << 14)
                                    + ((size_t)(wave & 3) << 12) + ((size_t)lane << 4);

    v16f acc[2][2];
#pragma unroll
    for (int i = 0; i < 2; i++)
#pragma unroll
        for (int j = 0; j < 2; j++) acc[i][j] = (v16f)(0.0f);

    // stage tap into buffer buf: exactly 6 VMEM instr per wave, unconditional
    // (OOB lanes read the zero page) -> vmcnt counting is exec-uniform.
    auto stage = [&](int tap, int buf) {
        const int dy = tap / 3 - 1;
        const int dx = tap % 3 - 1;
        const unsigned char* bs = bsrc0 + ((size_t)tap << 14);
        unsigned char* bdst = Bs[buf] + (wave << 12);
#pragma unroll
        for (int q = 0; q < 4; ++q)
            GLOAD_LDS16(bs + (q << 10), bdst + (q << 10));
        unsigned char* adst = At[buf] + (wave << 11);
#pragma unroll
        for (int it = 0; it < 2; ++it) {
            const int region = (wave << 1) + it;      // 0..15
            const int row = (region << 3) + srow;     // 0..127 m-local
            const int iyl = region >> 3;              // row>>6, uniform per instr
            const int ny  = ((iy0 + iyl) << 1) + dy;
            const int nx  = ((row & 63) << 1) + dx;
            const unsigned char* asrc =
                (((unsigned)ny < 128u) & ((unsigned)nx < 128u))
                    ? F8 + ((rowA0 + ((long)ny << 7) + nx) << 7) + (chp << 4)
                    : zp + (chp << 4);
            GLOAD_LDS16(asrc, adst + (it << 10));
        }
    };

    auto compute = [&](int buf) {
#pragma unroll
        for (int seg = 0; seg < 8; ++seg) {   // K=128 -> 8 x (32x32x16)
            const int q = seg ^ xorl;         // phys chunk (row&7 == l31&7)
            long long a[2], b2[2];
#pragma unroll
            for (int i = 0; i < 2; i++)
                a[i] = *(const long long*)(At[buf] + ((wm + (i << 5) + l31) << 7) + (q << 4) + (hh << 3));
#pragma unroll
            for (int j = 0; j < 2; j++)
                b2[j] = *(const long long*)(Bs[buf] + ((wn + (j << 5) + l31) << 7) + (q << 4) + (hh << 3));
            __builtin_amdgcn_s_setprio(1);
#pragma unroll
            for (int i = 0; i < 2; i++)
#pragma unroll
                for (int j = 0; j < 2; j++)
                    acc[i][j] = __builtin_amdgcn_mfma_f32_32x32x16_fp8_fp8(a[i], b2[j], acc[i][j], 0, 0, 0);
            __builtin_amdgcn_s_setprio(0);
        }
    };

    stage(0, 0);                              // prologue: 2 taps in flight
    stage(1, 1);

#pragma unroll
    for (int tap = 0; tap < 9; ++tap) {
        const int buf = tap % 3;              // compile-time after unroll
        if (tap < 7) {
            stage(tap + 2, (tap + 2) % 3);
            // own 6 oldest (tap's stage) drained; 12 younger stay in flight.
            asm volatile("s_waitcnt vmcnt(12)\ns_barrier" ::: "memory");
        } else if (tap == 7) {
            asm volatile("s_waitcnt vmcnt(6)\ns_barrier" ::: "memory");
        } else {
            asm volatile("s_waitcnt vmcnt(0)\ns_barrier" ::: "memory");
        }
        compute(tap == 8 ? 2 : buf);          // (9-1)%3 == 2; keep expr constant-foldable
        // protect buffer reuse: next iter's stage overwrites buf read 2 iters ago.
        asm volatile("s_barrier" ::: "memory");
    }

    // epilogue: 32x32 D layout col=lane&31, row=(reg&3)+8*(reg>>2)+4*(lane>>5)  [m74/m101]
    // nt stores: output stream does not allocate/thrash L2.
#pragma unroll
    for (int i = 0; i < 2; i++)
#pragma unroll
        for (int j = 0; j < 2; j++) {
            const int gcol = wn + (j << 5) + l31;
#pragma unroll
            for (int r = 0; r < 16; ++r) {
                const int grow = m0 + wm + (i << 5) + (r & 3) + ((r >> 2) << 3) + (hh << 2);
                __builtin_nontemporal_store(acc[i][j][r], &out[(size_t)grow * 256 + gcol]);
            }
        }
}

// ---- fallback: direct fp32 conv ----
__global__ void naive_conv_kernel(const float* __restrict__ feats,
                                  const float* __restrict__ w,
                                  float* __restrict__ out) {
    int m = blockIdx.x;
    int n = threadIdx.x;
    int bb = m >> 12, iy = (m >> 6) & 63, ix = m & 63;
    float acc = 0.f;
    for (int tap = 0; tap < 9; ++tap) {
        int ny = 2 * iy + tap / 3 - 1;
        int nx = 2 * ix + tap % 3 - 1;
        if ((unsigned)ny < 128u && (unsigned)nx < 128u) {
            const float* fr = feats + ((size_t)((bb << 14) + (ny << 7) + nx) << 7);
            const float* wr = w + tap * 32768 + n;
            for (int c = 0; c < 128; ++c) acc += fr[c] * wr[c * 256];
        }
    }
    out[(size_t)m * 256 + n] = acc;
}

extern "C" void kernel_launch(void* const* d_in, const int* in_sizes, int n_in,
                              void* d_out, int out_size, void* d_ws, size_t ws_size,
                              hipStream_t stream) {
    const float* feats  = (const float*)d_in[0];
    const float* weight = (const float*)d_in[1];
    const float* alpha  = (const float*)d_in[2];
    float* out = (float*)d_out;

    const size_t NEED = (size_t)F8_BYTES + BW_BYTES + 128;   // + zero page
    if (ws_size >= NEED) {
        unsigned char* F8 = (unsigned char*)d_ws;
        unsigned char* Bw = F8 + F8_BYTES;
        prep_kernel<<<8336, 256, 0, stream>>>(feats, weight, alpha, F8, Bw, out);
        gemm_conv_kernel<<<256, 512, 0, stream>>>(F8, Bw, out);
    } else {
        coords_alpha_kernel<<<128, 256, 0, stream>>>(out, alpha);
        naive_conv_kernel<<<32768, 256, 0, stream>>>(feats, weight, out);
    }
}

// Round 5
// 132.409 us; speedup vs baseline: 1.0265x; 1.0265x over previous
//
#include <hip/hip_runtime.h>

// B=8, H=W=128, Cin=128, Cout=256, 3x3 stride2 pad1 -> OH=OW=64.
// Implicit GEMM: M=32768, N=256, K=1152 (9 taps x 128).
// d_out (f32): out_feats[32768*256] | out_coords[32768*3] | alpha[1]
// R12: FUSE feats fp32->fp8 conversion into the gemm. Each block converts its
//      5-input-row band (320KB fp32) into a PERSISTENT 81KB LDS band read by
//      all 9 taps (no per-tap A staging, no F8 intermediate, no feats prep
//      pass). prep shrinks to weight-only (~2us). B double-buffered via
//      global_load_lds + counted vmcnt(4). Tile 128m x 256n, 256 blocks x 512.

#define OUT_FEATS_ELEMS (32768 * 256)
#define OUT_COORDS_OFF  OUT_FEATS_ELEMS
#define ALPHA_OFF       (OUT_FEATS_ELEMS + 32768 * 3)

#define BW_BYTES   (18 * 16384)

typedef float v16f __attribute__((ext_vector_type(16)));

__device__ __forceinline__ unsigned pk4fp8(float a, float b, float c, float d) {
    unsigned u = 0;
    u = __builtin_amdgcn_cvt_pk_fp8_f32(a, b, u, false);  // bytes 0,1
    u = __builtin_amdgcn_cvt_pk_fp8_f32(c, d, u, true);   // bytes 2,3
    return u;
}

#define GLOAD_LDS16(SRC, DST)                                                  \
    __builtin_amdgcn_global_load_lds(                                          \
        (const __attribute__((address_space(1))) void*)(SRC),                  \
        (__attribute__((address_space(3))) void*)(DST), 16, 0, 0)

// ---- weight prep: pre-swizzled fp8 B images + coords + alpha ----
// Image[t=nb*9+tap][row 0..127][ch 0..7] (16B chunks):
//   fp8 of w[k = tap*128 + (ch^(row&7))*16 + j][n = nb*128 + row], j=0..15
__global__ void wprep_kernel(const float* __restrict__ w,
                             const float* __restrict__ alpha,
                             unsigned char* __restrict__ Bw,
                             float* __restrict__ out) {
    int cid = blockIdx.x * 256 + threadIdx.x;     // 0..36863
    if (cid < 32768) {                            // coords
        int b = cid >> 12, iy = (cid >> 6) & 63, ix = cid & 63;
        float* c = out + OUT_COORDS_OFF + (size_t)cid * 3;
        c[0] = (float)b; c[1] = (float)iy; c[2] = (float)ix;
        if (cid == 0) out[ALPHA_OFF] = alpha[0];
    }
    if (cid < 18432) {                            // 18 images x 128 rows x 8 chunks
        int ch  = cid & 7;
        int row = (cid >> 3) & 127;
        int t   = cid >> 10;                      // 0..17 = nb*9 + tap
        int nb  = (t >= 9) ? 1 : 0;
        int tap = t - 9 * nb;
        int chp = ch ^ (row & 7);
        int n   = (nb << 7) + row;
        int kb  = (tap << 7) + (chp << 4);
        unsigned u[4];
#pragma unroll
        for (int q = 0; q < 4; ++q) {
            float f0 = w[(size_t)(kb + 4 * q + 0) * 256 + n];
            float f1 = w[(size_t)(kb + 4 * q + 1) * 256 + n];
            float f2 = w[(size_t)(kb + 4 * q + 2) * 256 + n];
            float f3 = w[(size_t)(kb + 4 * q + 3) * 256 + n];
            u[q] = pk4fp8(f0, f1, f2, f3);
        }
        uint4 r; r.x = u[0]; r.y = u[1]; r.z = u[2]; r.w = u[3];
        *(uint4*)(Bw + (size_t)cid * 16) = r;
    }
}

// ---- coords for fallback path ----
__global__ void coords_alpha_kernel(float* __restrict__ out, const float* __restrict__ alpha) {
    int i = blockIdx.x * 256 + threadIdx.x;
    int b = i >> 12, iy = (i >> 6) & 63, ix = i & 63;
    float* c = out + OUT_COORDS_OFF + (size_t)i * 3;
    c[0] = (float)b; c[1] = (float)iy; c[2] = (float)ix;
    if (i == 0) out[ALPHA_OFF] = alpha[0];
}

// ---- fused conv GEMM: persistent LDS A-band (5 input rows, fp8, swizzled),
//      9-tap loop stages only B; fp8 32x32x16 MFMA; counted vmcnt ----
// Aband layout: [r 0..4][nxp 0..129][128B of k-chans], chunk c stored at
//   c ^ ((nxp>>1)&7). nxp = input_nx + 1 (nxp=0 is the nx=-1 zero pad).
// r = ny - (2*iy0 - 1). Row r=0 zeroed when iy0==0 (ny=-1).
__global__ __launch_bounds__(512, 1) void gemm_conv_kernel(
    const float* __restrict__ feats,         // fp32 [B*128*128][128]
    const unsigned char* __restrict__ Bw,    // pre-swizzled fp8 B images (18 x 16KB)
    float* __restrict__ out)                 // [32768][256]
{
    __shared__ unsigned char Aband[5 * 130 * 128];   // 83,200 B
    __shared__ unsigned char Bs[2][256 * 128];       // 2 x 32,768 B

    const int tid  = threadIdx.x;
    const int bid  = blockIdx.x;             // 0..255
    // XCD-aware: XCD (bid&7) owns batch bb=(bid&7).
    const int my   = ((bid & 7) << 5) + (bid >> 3);
    const int m0   = my << 7;
    const int bb   = my >> 5;                // == bid & 7
    const int iy0  = ((my & 31) << 1);       // 0..62 even

    const int lane = tid & 63, wave = tid >> 6;  // wave 0..7
    const int wm   = (wave >> 2) << 6;       // 0 / 64
    const int wn   = (wave & 3) << 6;        // 0 / 64 / 128 / 192
    const int l31  = lane & 31;
    const int hh   = lane >> 5;              // k-half select
    const int xorl = l31 & 7;

    // ---- phase 0: zero pads ----
    if (tid < 40) {                          // nxp=0 column: 5 rows x 8 chunks
        const int r = tid >> 3, c = tid & 7; // key((0)>>1)=0 -> chunk stored at c
        uint4 z; z.x = 0u; z.y = 0u; z.z = 0u; z.w = 0u;
        *(uint4*)(Aband + ((r * 130) << 7) + (c << 4)) = z;
    }
    if (iy0 == 0) {                          // row r=0 (ny=-1): 130 x 8 chunks
        for (int z = tid; z < 1040; z += 512) {
            const int nxp = z >> 3, c = z & 7;
            uint4 zz; zz.x = 0u; zz.y = 0u; zz.z = 0u; zz.w = 0u;
            *(uint4*)(Aband + (nxp << 7) + ((c ^ ((nxp >> 1) & 7)) << 4)) = zz;
        }
    }

    // ---- phase 1: load + convert the 5-row fp32 band into LDS ----
    {
        const int vstart = (iy0 == 0) ? 1 : 0;      // skip ny=-1 row
        const int iters  = (5 - vstart) << 3;       // 8 float4 per row per thread
        const int ny0    = (iy0 << 1) - 1;
        for (int it = 0; it < iters; ++it) {
            const int o   = (tid + (it << 9)) << 4; // byte offset in valid fp32 region
            const int r   = vstart + (o >> 16);     // band row
            const int br  = o & 65535;
            const int nx  = br >> 9;
            const int ch0 = (br & 511) >> 2;        // float idx 0..124 step 4
            const float4 f = *(const float4*)(feats +
                ((((size_t)(bb << 14) + (ny0 + r) * 128 + nx)) << 7) + ch0);
            const unsigned u = pk4fp8(f.x, f.y, f.z, f.w);
            const int c   = ch0 >> 4;
            const int nxp = nx + 1;
            *(unsigned*)(Aband + ((r * 130 + nxp) << 7)
                         + ((c ^ ((nxp >> 1) & 7)) << 4) + (ch0 & 15)) = u;
        }
    }
    __syncthreads();                          // band visible to all waves

    // ---- B staging machinery (4 x global_load_lds per wave per tap) ----
    const unsigned char* bsrc0 = Bw + ((size_t)((wave >> 2) * 9) << 14)
                                    + ((size_t)(wave & 3) << 12) + ((size_t)lane << 4);
    auto stageB = [&](int tap, int buf) {
        const unsigned char* bs = bsrc0 + ((size_t)tap << 14);
        unsigned char* bdst = Bs[buf] + (wave << 12);
#pragma unroll
        for (int q = 0; q < 4; ++q)
            GLOAD_LDS16(bs + (q << 10), bdst + (q << 10));
    };

    v16f acc[2][2];
#pragma unroll
    for (int i = 0; i < 2; i++)
#pragma unroll
        for (int j = 0; j < 2; j++) acc[i][j] = (v16f)(0.0f);

    auto computeTap = [&](int buf, int dy, int dx) {
        const int bandrow = (wm >> 5) + dy + 1;     // wave-uniform, 0..4
        int abase[2], akey[2];
#pragma unroll
        for (int i = 0; i < 2; ++i) {
            const int ixv = (i << 5) + l31;
            const int nxp = (ixv << 1) + dx + 1;    // 0..128
            abase[i] = ((bandrow * 130 + nxp) << 7) + (hh << 3);
            akey[i]  = (nxp >> 1) & 7;
        }
#pragma unroll
        for (int seg = 0; seg < 8; ++seg) {   // K=128 -> 8 x (32x32x16)
            long long a[2], b2[2];
#pragma unroll
            for (int i = 0; i < 2; i++)
                a[i] = *(const long long*)(Aband + abase[i] + ((seg ^ akey[i]) << 4));
#pragma unroll
            for (int j = 0; j < 2; j++)
                b2[j] = *(const long long*)(Bs[buf] + ((wn + (j << 5) + l31) << 7)
                                            + ((seg ^ xorl) << 4) + (hh << 3));
            __builtin_amdgcn_s_setprio(1);
#pragma unroll
            for (int i = 0; i < 2; i++)
#pragma unroll
                for (int j = 0; j < 2; j++)
                    acc[i][j] = __builtin_amdgcn_mfma_f32_32x32x16_fp8_fp8(a[i], b2[j], acc[i][j], 0, 0, 0);
            __builtin_amdgcn_s_setprio(0);
        }
    };

    stageB(0, 0);                             // prefetch tap 0

#pragma unroll
    for (int tap = 0; tap < 9; ++tap) {
        if (tap < 8) {
            stageB(tap + 1, (tap + 1) & 1);
            // own 4 oldest (tap's B) drained; next tap's 4 stay in flight.
            asm volatile("s_waitcnt vmcnt(4)\ns_barrier" ::: "memory");
        } else {
            asm volatile("s_waitcnt vmcnt(0)\ns_barrier" ::: "memory");
        }
        computeTap(tap & 1, tap / 3 - 1, tap % 3 - 1);
        if (tap < 8)                          // protect buf reuse by next stage
            asm volatile("s_barrier" ::: "memory");
    }

    // epilogue: 32x32 D layout col=lane&31, row=(reg&3)+8*(reg>>2)+4*(lane>>5)  [m74/m101]
    // nt stores: output stream does not allocate/thrash L2.
#pragma unroll
    for (int i = 0; i < 2; i++)
#pragma unroll
        for (int j = 0; j < 2; j++) {
            const int gcol = wn + (j << 5) + l31;
#pragma unroll
            for (int r = 0; r < 16; ++r) {
                const int grow = m0 + wm + (i << 5) + (r & 3) + ((r >> 2) << 3) + (hh << 2);
                __builtin_nontemporal_store(acc[i][j][r], &out[(size_t)grow * 256 + gcol]);
            }
        }
}

// ---- fallback: direct fp32 conv ----
__global__ void naive_conv_kernel(const float* __restrict__ feats,
                                  const float* __restrict__ w,
                                  float* __restrict__ out) {
    int m = blockIdx.x;
    int n = threadIdx.x;
    int bb = m >> 12, iy = (m >> 6) & 63, ix = m & 63;
    float acc = 0.f;
    for (int tap = 0; tap < 9; ++tap) {
        int ny = 2 * iy + tap / 3 - 1;
        int nx = 2 * ix + tap % 3 - 1;
        if ((unsigned)ny < 128u && (unsigned)nx < 128u) {
            const float* fr = feats + ((size_t)((bb << 14) + (ny << 7) + nx) << 7);
            const float* wr = w + tap * 32768 + n;
            for (int c = 0; c < 128; ++c) acc += fr[c] * wr[c * 256];
        }
    }
    out[(size_t)m * 256 + n] = acc;
}

extern "C" void kernel_launch(void* const* d_in, const int* in_sizes, int n_in,
                              void* d_out, int out_size, void* d_ws, size_t ws_size,
                              hipStream_t stream) {
    const float* feats  = (const float*)d_in[0];
    const float* weight = (const float*)d_in[1];
    const float* alpha  = (const float*)d_in[2];
    float* out = (float*)d_out;

    const size_t NEED = (size_t)BW_BYTES;
    if (ws_size >= NEED) {
        unsigned char* Bw = (unsigned char*)d_ws;
        wprep_kernel<<<144, 256, 0, stream>>>(weight, alpha, Bw, out);
        gemm_conv_kernel<<<256, 512, 0, stream>>>(feats, Bw, out);
    } else {
        coords_alpha_kernel<<<128, 256, 0, stream>>>(out, alpha);
        naive_conv_kernel<<<32768, 256, 0, stream>>>(feats, weight, out);
    }
}